// Round 1
// baseline (425.721 us; speedup 1.0000x reference)
//
#include <hip/hip_runtime.h>

// Problem constants
//  B=8, C=128, H=W=128, HW=16384
typedef __attribute__((ext_vector_type(4))) float f32x4;
typedef __attribute__((ext_vector_type(8))) short s16x8;
typedef __bf16 bf16x8 __attribute__((ext_vector_type(8)));

__device__ __forceinline__ short f2bf(float f) {
  union { float f; unsigned u; } c; c.f = f;
  unsigned r = c.u + 0x7fffu + ((c.u >> 16) & 1u);
  return (short)(r >> 16);
}
__device__ __forceinline__ float bf2f(short s) {
  union { unsigned u; float f; } c; c.u = ((unsigned)(unsigned short)s) << 16;
  return c.f;
}

// ---------------------------------------------------------------------------
// K1: fused LayerNorm (over C=128) + conv1x1 GEMM, output bf16.
//  grid: 1024 blocks q-path (cur/ln2/q_w1 -> Yq[131072][128])
//      + 2048 blocks kv-path (pre/ln1/kv_w1 halves -> Ykv[131072][256])
// ---------------------------------------------------------------------------
__global__ __launch_bounds__(256, 2)
void k1_ln_gemm(const float* __restrict__ cur, const float* __restrict__ pre,
                const float* __restrict__ ln1w, const float* __restrict__ ln1b,
                const float* __restrict__ ln2w, const float* __restrict__ ln2b,
                const float* __restrict__ qw1, const float* __restrict__ qb1,
                const float* __restrict__ kvw1, const float* __restrict__ kvb1,
                short* __restrict__ Yq, short* __restrict__ Ykv)
{
  __shared__ short At[128][136];   // pitch 272B: 16B aligned, 2-way bank alias (free)
  __shared__ short Wt[128][136];
  const int tid = threadIdx.x;
  const int blk = blockIdx.x;

  const float *X, *lw, *lb, *Wm, *bias;
  short* Yout; int ldy, noff, mblk;
  if (blk < 1024) {
    mblk = blk; X = cur; lw = ln2w; lb = ln2b; Wm = qw1; bias = qb1;
    Yout = Yq; ldy = 128; noff = 0;
  } else {
    const int t2 = blk - 1024; const int hfn = t2 >> 10; mblk = t2 & 1023;
    X = pre; lw = ln1w; lb = ln1b; Wm = kvw1 + hfn * 16384; bias = kvb1 + hfn * 128;
    Yout = Ykv; ldy = 256; noff = hfn * 128;
  }

  const int r = tid >> 1;
  const int hf = tid & 1;

  // stage A-tile (128 rows x 128 c) with LayerNorm; 2 threads per row
  {
    const float* src = X + ((size_t)(mblk * 128 + r)) * 128 + hf * 64;
    float f[64];
    float s1 = 0.f, s2 = 0.f;
#pragma unroll
    for (int i = 0; i < 16; i++) {
      f32x4 v = *(const f32x4*)(src + i * 4);
#pragma unroll
      for (int j = 0; j < 4; j++) { float x = v[j]; f[i * 4 + j] = x; s1 += x; s2 += x * x; }
    }
    s1 += __shfl_xor(s1, 1);
    s2 += __shfl_xor(s2, 1);
    const float mu = s1 * (1.f / 128.f);
    const float var = s2 * (1.f / 128.f) - mu * mu;
    const float rstd = rsqrtf(var + 1e-5f);
#pragma unroll
    for (int g = 0; g < 8; g++) {
      s16x8 o;
#pragma unroll
      for (int j = 0; j < 8; j++) {
        const int c = hf * 64 + g * 8 + j;
        const float xn = (f[g * 8 + j] - mu) * rstd;
        o[j] = f2bf(xn * lw[c] + lb[c]);
      }
      *(s16x8*)&At[r][hf * 64 + g * 8] = o;
    }
  }
  // stage W-tile (row o, col c) -> bf16
  {
    const float* wsrc = Wm + (size_t)r * 128 + hf * 64;
#pragma unroll
    for (int g = 0; g < 8; g++) {
      s16x8 o;
#pragma unroll
      for (int j = 0; j < 8; j++) o[j] = f2bf(wsrc[g * 8 + j]);
      *(s16x8*)&Wt[r][hf * 64 + g * 8] = o;
    }
  }
  __syncthreads();

  const int wv = tid >> 6, lane = tid & 63;
  const int l16 = lane & 15, quad = lane >> 4, kof = quad * 8;
  f32x4 acc[2][8];
#pragma unroll
  for (int i = 0; i < 2; i++)
#pragma unroll
    for (int j = 0; j < 8; j++) acc[i][j] = (f32x4){0.f, 0.f, 0.f, 0.f};

#pragma unroll
  for (int ks = 0; ks < 4; ks++) {
    const int kb = ks * 32 + kof;
    const bf16x8 a0 = *(const bf16x8*)&At[wv * 32 + l16][kb];
    const bf16x8 a1 = *(const bf16x8*)&At[wv * 32 + 16 + l16][kb];
#pragma unroll
    for (int j = 0; j < 8; j++) {
      const bf16x8 bv = *(const bf16x8*)&Wt[j * 16 + l16][kb];
      acc[0][j] = __builtin_amdgcn_mfma_f32_16x16x32_bf16(a0, bv, acc[0][j], 0, 0, 0);
      acc[1][j] = __builtin_amdgcn_mfma_f32_16x16x32_bf16(a1, bv, acc[1][j], 0, 0, 0);
    }
  }
  // epilogue: D[row=pos][col=o]; add conv bias, store bf16
#pragma unroll
  for (int i = 0; i < 2; i++) {
    const int mg = mblk * 128 + wv * 32 + i * 16 + quad * 4;
#pragma unroll
    for (int j = 0; j < 8; j++) {
      const int o = j * 16 + l16;
      const float bsv = bias[o];
#pragma unroll
      for (int rg = 0; rg < 4; rg++) {
        Yout[(size_t)(mg + rg) * ldy + noff + o] = f2bf(acc[i][j][rg] + bsv);
      }
    }
  }
}

// ---------------------------------------------------------------------------
// K2: depthwise 3x3 conv (NHWC) + bias; also per-(b,channel) sum of squares
//     for q (-> nq) and k (-> nk) l2 norms.
//  grid 6144: seg(3) x (b*H = 1024) x chalf(2); block handles one image row,
//  64 channels.
// ---------------------------------------------------------------------------
__global__ __launch_bounds__(256, 3)
void k2_dwconv(const short* __restrict__ Yq, const short* __restrict__ Ykv,
               const float* __restrict__ qw2, const float* __restrict__ qb2,
               const float* __restrict__ kvw2, const float* __restrict__ kvb2,
               short* __restrict__ qo, short* __restrict__ ko, short* __restrict__ vo,
               float* __restrict__ nq, float* __restrict__ nk)
{
  __shared__ short tile[3][130][64];
  __shared__ float red[256];
  const int tid = threadIdx.x;
  const int bx = blockIdx.x;
  const int seg = bx >> 11;       // 0:q 1:k 2:v
  const int rem = bx & 2047;
  const int bh = rem >> 1;
  const int chalf = rem & 1;
  const int b = bh >> 7, h = bh & 127;
  const int co0 = chalf * 64;

  const short* in; int ld; int cin0; const float* w2; const float* b2p;
  short* outp; float* np;
  if (seg == 0)      { in = Yq;  ld = 128; cin0 = co0;       w2 = qw2;  b2p = qb2;  outp = qo; np = nq; }
  else if (seg == 1) { in = Ykv; ld = 256; cin0 = co0;       w2 = kvw2; b2p = kvb2; outp = ko; np = nk; }
  else               { in = Ykv; ld = 256; cin0 = 128 + co0; w2 = kvw2; b2p = kvb2; outp = vo; np = nullptr; }

  // stage rows h-1,h,h+1 (w-halo cols 0 & 129 zeroed)
  {
    const int wi = tid >> 3;
    const int cg = (tid & 7) * 8;
#pragma unroll
    for (int dr = 0; dr < 3; dr++) {
      const int hh = h + dr - 1;
      const bool valid = (hh >= 0) && (hh < 128);
      const short* rowp = in + ((size_t)(b * 128 + (valid ? hh : 0))) * 128 * ld + cin0 + cg;
#pragma unroll
      for (int it = 0; it < 4; it++) {
        const int w = wi + it * 32;
        s16x8 v = {0, 0, 0, 0, 0, 0, 0, 0};
        if (valid) v = *(const s16x8*)(rowp + (size_t)w * ld);
        *(s16x8*)&tile[dr][w + 1][cg] = v;
      }
    }
    if (tid < 192) { const int dr = tid >> 6, c = tid & 63; tile[dr][0][c] = 0; tile[dr][129][c] = 0; }
  }
  __syncthreads();

  const int c = tid & 63;
  const int wg = tid >> 6;
  float wt[9];
#pragma unroll
  for (int j = 0; j < 9; j++) wt[j] = w2[(cin0 + c) * 9 + j];
  const float bsv = b2p[cin0 + c];

  float ss = 0.f;
  const size_t rowbase = ((size_t)((b * 128 + h) * 128)) * 128 + co0 + c;
  for (int it = 0; it < 32; it++) {
    const int w = wg + it * 4;
    float s = bsv;
#pragma unroll
    for (int dh = 0; dh < 3; dh++)
#pragma unroll
      for (int dw = 0; dw < 3; dw++)
        s += wt[dh * 3 + dw] * bf2f(tile[dh][w + dw][c]);
    outp[rowbase + (size_t)w * 128] = f2bf(s);
    ss += s * s;
  }
  red[tid] = ss;
  __syncthreads();
  if (seg < 2 && tid < 64) {
    const float t = red[tid] + red[tid + 64] + red[tid + 128] + red[tid + 192];
    atomicAdd(np + b * 128 + co0 + tid, t);
  }
}

// ---------------------------------------------------------------------------
// K3: Gram partials  G[b][c][d] = sum_n q[b][n][c] * k[b][n][d]
//  split-K: grid 256 = B x 32; each block does 512 n, writes its own partial.
//  LDS transpose staging so MFMA frags are k-contiguous.
// ---------------------------------------------------------------------------
__global__ __launch_bounds__(256, 2)
void k3_gram(const short* __restrict__ qi, const short* __restrict__ ki,
             float* __restrict__ Gp)
{
  __shared__ short qT[128][40];   // pitch 80B: 16B aligned
  __shared__ short kT[128][40];
  const int tid = threadIdx.x;
  const int b = blockIdx.x >> 5, ksp = blockIdx.x & 31;
  const int wv = tid >> 6, lane = tid & 63, l16 = lane & 15, quad = lane >> 4, kof = quad * 8;
  const int nl = tid >> 3;
  const int c0 = (tid & 7) * 16;
  f32x4 acc[2][8];
#pragma unroll
  for (int i = 0; i < 2; i++)
#pragma unroll
    for (int j = 0; j < 8; j++) acc[i][j] = (f32x4){0.f, 0.f, 0.f, 0.f};

  const size_t base = ((size_t)(b * 16384 + ksp * 512)) * 128 + (size_t)nl * 128 + c0;
  for (int ch = 0; ch < 16; ch++) {
    const size_t rb = base + (size_t)ch * 32 * 128;
    const s16x8 q0 = *(const s16x8*)(qi + rb);
    const s16x8 q1 = *(const s16x8*)(qi + rb + 8);
    const s16x8 k0 = *(const s16x8*)(ki + rb);
    const s16x8 k1 = *(const s16x8*)(ki + rb + 8);
    __syncthreads();   // previous iter MFMA reads done before overwrite
#pragma unroll
    for (int j = 0; j < 8; j++) {
      qT[c0 + j][nl] = q0[j];
      qT[c0 + 8 + j][nl] = q1[j];
      kT[c0 + j][nl] = k0[j];
      kT[c0 + 8 + j][nl] = k1[j];
    }
    __syncthreads();
    const bf16x8 a0 = *(const bf16x8*)&qT[wv * 32 + l16][kof];
    const bf16x8 a1 = *(const bf16x8*)&qT[wv * 32 + 16 + l16][kof];
#pragma unroll
    for (int j = 0; j < 8; j++) {
      const bf16x8 bv = *(const bf16x8*)&kT[j * 16 + l16][kof];
      acc[0][j] = __builtin_amdgcn_mfma_f32_16x16x32_bf16(a0, bv, acc[0][j], 0, 0, 0);
      acc[1][j] = __builtin_amdgcn_mfma_f32_16x16x32_bf16(a1, bv, acc[1][j], 0, 0, 0);
    }
  }
  float* gp = Gp + ((size_t)(ksp * 8 + b)) * 16384;
#pragma unroll
  for (int i = 0; i < 2; i++)
#pragma unroll
    for (int j = 0; j < 8; j++)
#pragma unroll
      for (int rg = 0; rg < 4; rg++)
        gp[(wv * 32 + i * 16 + quad * 4 + rg) * 128 + j * 16 + l16] = acc[i][j][rg];
}

// ---------------------------------------------------------------------------
// K4a: reduce split-K partials, apply l2-norm rescale, softmax over d -> att
//  grid 128 = B x 16 row-chunks of 8; half-wave (32 lanes) per row.
// ---------------------------------------------------------------------------
__global__ void k4a_softmax(const float* __restrict__ Gp,
                            const float* __restrict__ nq, const float* __restrict__ nk,
                            float* __restrict__ att)
{
  const int tid = threadIdx.x;
  const int b = blockIdx.x >> 4, cb = (blockIdx.x & 15) * 8;
  const int r = tid >> 5, dsi = tid & 31;
  const int c = cb + r, d0 = dsi * 4;
  f32x4 a = (f32x4){0.f, 0.f, 0.f, 0.f};
  for (int ks = 0; ks < 32; ks++) {
    a += *(const f32x4*)(Gp + ((size_t)(ks * 8 + b)) * 16384 + c * 128 + d0);
  }
  const float qn = fmaxf(sqrtf(nq[b * 128 + c]), 1e-12f);
  f32x4 sc;
#pragma unroll
  for (int j = 0; j < 4; j++) {
    const float kn = fmaxf(sqrtf(nk[b * 128 + d0 + j]), 1e-12f);
    sc[j] = a[j] / (qn * kn);
  }
  float mx = fmaxf(fmaxf(sc[0], sc[1]), fmaxf(sc[2], sc[3]));
#pragma unroll
  for (int m = 16; m >= 1; m >>= 1) mx = fmaxf(mx, __shfl_xor(mx, m));
  f32x4 e; float sum = 0.f;
#pragma unroll
  for (int j = 0; j < 4; j++) { e[j] = __expf(sc[j] - mx); sum += e[j]; }
#pragma unroll
  for (int m = 16; m >= 1; m >>= 1) sum += __shfl_xor(sum, m);
  const float inv = 1.f / sum;
  f32x4 o;
#pragma unroll
  for (int j = 0; j < 4; j++) o[j] = e[j] * inv;
  *(f32x4*)(att + (size_t)b * 16384 + c * 128 + d0) = o;
}

// ---------------------------------------------------------------------------
// K4b: M[b][o][d] = sum_c out_w[o][c] * att[b][c][d]  (tiny GEMM, bf16 out)
//  grid 64 = B x 8 d-chunks of 16.
// ---------------------------------------------------------------------------
__global__ void k4b_mw(const float* __restrict__ att, const float* __restrict__ outw,
                       short* __restrict__ Mb)
{
  const int tid = threadIdx.x;
  const int b = blockIdx.x >> 3, db = (blockIdx.x & 7) * 16;
  const int o = tid & 127, dg = tid >> 7;
  const int d0 = db + dg * 8;
  float acc[8] = {0.f, 0.f, 0.f, 0.f, 0.f, 0.f, 0.f, 0.f};
  const float* ar = att + (size_t)b * 16384 + d0;
  const float* wr = outw + o * 128;
  for (int cc = 0; cc < 128; cc++) {
    const float wvv = wr[cc];
    const f32x4 a0 = *(const f32x4*)(ar + cc * 128);
    const f32x4 a1 = *(const f32x4*)(ar + cc * 128 + 4);
    acc[0] += wvv * a0[0]; acc[1] += wvv * a0[1]; acc[2] += wvv * a0[2]; acc[3] += wvv * a0[3];
    acc[4] += wvv * a1[0]; acc[5] += wvv * a1[1]; acc[6] += wvv * a1[2]; acc[7] += wvv * a1[3];
  }
  short* mp = Mb + ((size_t)(b * 128 + o)) * 128 + d0;
#pragma unroll
  for (int j = 0; j < 8; j++) mp[j] = f2bf(acc[j]);
}

// ---------------------------------------------------------------------------
// K5: out[b][n][o] = sum_d M[b][o][d] * v[b][n][d] + out_b[o] + cur[b][n][o]
//  grid 1024 = B x 128 pos-chunks of 128. v tile staged in LDS; M frags from
//  global (64 KiB, L2-hot). fp32 epilogue with residual.
// ---------------------------------------------------------------------------
__global__ __launch_bounds__(256, 2)
void k5_out(const short* __restrict__ Mb, const short* __restrict__ vi,
            const float* __restrict__ outb, const float* __restrict__ cur,
            float* __restrict__ out)
{
  __shared__ short Vt[128][136];
  const int tid = threadIdx.x;
  const int b = blockIdx.x >> 7, nb = (blockIdx.x & 127) * 128;
  const int r = tid >> 1, hf = tid & 1;
  {
    const short* src = vi + ((size_t)(b * 16384 + nb + r)) * 128 + hf * 64;
#pragma unroll
    for (int g = 0; g < 8; g++)
      *(s16x8*)&Vt[r][hf * 64 + g * 8] = *(const s16x8*)(src + g * 8);
  }
  __syncthreads();
  const int wv = tid >> 6, lane = tid & 63, l16 = lane & 15, quad = lane >> 4, kof = quad * 8;
  f32x4 acc[2][8];
#pragma unroll
  for (int i = 0; i < 2; i++)
#pragma unroll
    for (int j = 0; j < 8; j++) acc[i][j] = (f32x4){0.f, 0.f, 0.f, 0.f};

  const short* m0 = Mb + ((size_t)(b * 128 + wv * 32 + l16)) * 128;
  const short* m1 = m0 + 16 * 128;
#pragma unroll
  for (int ks = 0; ks < 4; ks++) {
    const int kb = ks * 32 + kof;
    const bf16x8 a0 = *(const bf16x8*)(m0 + kb);
    const bf16x8 a1 = *(const bf16x8*)(m1 + kb);
#pragma unroll
    for (int j = 0; j < 8; j++) {
      const bf16x8 bv = *(const bf16x8*)&Vt[j * 16 + l16][kb];
      acc[0][j] = __builtin_amdgcn_mfma_f32_16x16x32_bf16(a0, bv, acc[0][j], 0, 0, 0);
      acc[1][j] = __builtin_amdgcn_mfma_f32_16x16x32_bf16(a1, bv, acc[1][j], 0, 0, 0);
    }
  }
#pragma unroll
  for (int i = 0; i < 2; i++) {
    const int o0 = wv * 32 + i * 16 + quad * 4;
    const f32x4 bias = *(const f32x4*)(outb + o0);
#pragma unroll
    for (int j = 0; j < 8; j++) {
      const int pos = nb + j * 16 + l16;
      const size_t idx = ((size_t)(b * 16384 + pos)) * 128 + o0;
      const f32x4 cv = *(const f32x4*)(cur + idx);
      f32x4 rr;
#pragma unroll
      for (int rg = 0; rg < 4; rg++) rr[rg] = acc[i][j][rg] + bias[rg] + cv[rg];
      *(f32x4*)(out + idx) = rr;
    }
  }
}

// ---------------------------------------------------------------------------
extern "C" void kernel_launch(void* const* d_in, const int* in_sizes, int n_in,
                              void* d_out, int out_size, void* d_ws, size_t ws_size,
                              hipStream_t stream) {
  const float* pre  = (const float*)d_in[0];
  const float* cur  = (const float*)d_in[1];
  const float* ln1w = (const float*)d_in[2];
  const float* ln1b = (const float*)d_in[3];
  const float* ln2w = (const float*)d_in[4];
  const float* ln2b = (const float*)d_in[5];
  const float* qw1  = (const float*)d_in[6];
  const float* qb1  = (const float*)d_in[7];
  const float* qw2  = (const float*)d_in[8];
  const float* qb2  = (const float*)d_in[9];
  const float* kvw1 = (const float*)d_in[10];
  const float* kvb1 = (const float*)d_in[11];
  const float* kvw2 = (const float*)d_in[12];
  const float* kvb2 = (const float*)d_in[13];
  const float* outw = (const float*)d_in[14];
  const float* outb = (const float*)d_in[15];

  char* ws = (char*)d_ws;
  // Layout (bytes). Gpart/att/Mb alias Yq (dead after K2).
  short* Yq   = (short*)(ws + 0);            // 33554432 B
  short* Ykv  = (short*)(ws + 33554432);     // 67108864 B
  short* qo   = (short*)(ws + 100663296);    // 33554432 B
  short* ko   = (short*)(ws + 134217728);    // 33554432 B
  short* vo   = (short*)(ws + 167772160);    // 33554432 B
  float* nq   = (float*)(ws + 201326592);    // 4096 B
  float* nk   = (float*)(ws + 201330688);    // 4096 B
  float* Gp   = (float*)(ws + 0);            // 16777216 B (alias Yq)
  float* att  = (float*)(ws + 16777216);     // 524288 B   (alias Yq)
  short* Mb   = (short*)(ws + 17301504);     // 262144 B   (alias Yq)

  hipMemsetAsync(ws + 201326592, 0, 8192, stream);  // zero nq/nk for atomics

  hipLaunchKernelGGL(k1_ln_gemm, dim3(3072), dim3(256), 0, stream,
                     cur, pre, ln1w, ln1b, ln2w, ln2b, qw1, qb1, kvw1, kvb1, Yq, Ykv);
  hipLaunchKernelGGL(k2_dwconv, dim3(6144), dim3(256), 0, stream,
                     Yq, Ykv, qw2, qb2, kvw2, kvb2, qo, ko, vo, nq, nk);
  hipLaunchKernelGGL(k3_gram, dim3(256), dim3(256), 0, stream, qo, ko, Gp);
  hipLaunchKernelGGL(k4a_softmax, dim3(128), dim3(256), 0, stream, Gp, nq, nk, att);
  hipLaunchKernelGGL(k4b_mw, dim3(64), dim3(256), 0, stream, att, outw, Mb);
  hipLaunchKernelGGL(k5_out, dim3(1024), dim3(256), 0, stream, Mb, vo, outb, cur, (float*)d_out);
}

// Round 2
// 406.129 us; speedup vs baseline: 1.0482x; 1.0482x over previous
//
#include <hip/hip_runtime.h>

// B=8, C=128, H=W=128, HW=16384, positions total P=131072
typedef __attribute__((ext_vector_type(4))) float f32x4;
typedef __attribute__((ext_vector_type(2))) float f32x2;
typedef __attribute__((ext_vector_type(8))) short s16x8;
typedef __attribute__((ext_vector_type(4))) short s16x4;
typedef __bf16 bf16x8 __attribute__((ext_vector_type(8)));

__device__ __forceinline__ short f2bf(float f) {
  union { float f; unsigned u; } c; c.f = f;
  unsigned r = c.u + 0x7fffu + ((c.u >> 16) & 1u);
  return (short)(r >> 16);
}
__device__ __forceinline__ float bf2f(short s) {
  union { unsigned u; float f; } c; c.u = ((unsigned)(unsigned short)s) << 16;
  return c.f;
}

// ---------------------------------------------------------------------------
// K0: prep. W'[o][c] = lw[c]*W[o][c] (bf16); t1[o]=sum_c W'[o][c];
//     t2[o]=sum_c lb[c]*W[o][c] + conv_bias[o].   grid 3 (q,k,v), block 256.
// ---------------------------------------------------------------------------
__global__ void k0_prep(const float* __restrict__ qw1, const float* __restrict__ qb1,
                        const float* __restrict__ kvw1, const float* __restrict__ kvb1,
                        const float* __restrict__ ln1w, const float* __restrict__ ln1b,
                        const float* __restrict__ ln2w, const float* __restrict__ ln2b,
                        short* __restrict__ Wq, short* __restrict__ Wk, short* __restrict__ Wv,
                        float* __restrict__ T)  // [6][128]: t1q,t2q,t1k,t2k,t1v,t2v
{
  const int path = blockIdx.x;
  const int o = threadIdx.x >> 1, hf = threadIdx.x & 1;
  const float *W, *bias, *lw, *lb; short* Wo; float *t1, *t2;
  if (path == 0)      { W = qw1;            bias = qb1;       lw = ln2w; lb = ln2b; Wo = Wq; t1 = T;       t2 = T + 128; }
  else if (path == 1) { W = kvw1;           bias = kvb1;      lw = ln1w; lb = ln1b; Wo = Wk; t1 = T + 256; t2 = T + 384; }
  else                { W = kvw1 + 16384;   bias = kvb1+128;  lw = ln1w; lb = ln1b; Wo = Wv; t1 = T + 512; t2 = T + 640; }
  float s1 = 0.f, s2 = 0.f;
  for (int g = 0; g < 64; g++) {
    const int c = hf * 64 + g;
    const float w = W[o * 128 + c];
    const float wp = w * lw[c];
    s1 += wp; s2 += w * lb[c];
    Wo[o * 128 + c] = f2bf(wp);
  }
  s1 += __shfl_xor(s1, 1);
  s2 += __shfl_xor(s2, 1);
  if (hf == 0) { t1[o] = s1; t2[o] = s2 + bias[o]; }
}

// ---------------------------------------------------------------------------
// K1: GEMM on raw bf16 X with LN-affine epilogue.
//  grid 3072 = path(3) x 1024 pos-tiles of 128.
//  q,k: D rows=pos cols=o, planar store Y[c][n] packed 4-pos (8B).
//  v:   D rows=o cols=pos, row-major store Yv[n][c] packed 4-o (8B).
// ---------------------------------------------------------------------------
__global__ __launch_bounds__(256, 3)
void k1_ln_gemm(const float* __restrict__ cur, const float* __restrict__ pre,
                const short* __restrict__ Wq, const short* __restrict__ Wk,
                const short* __restrict__ Wv, const float* __restrict__ T,
                short* __restrict__ Yq, short* __restrict__ Yk, short* __restrict__ Yv)
{
  __shared__ __attribute__((aligned(16))) short At[128][136];
  __shared__ f32x2 rowstat[128];   // (mu, rstd) per local pos
  const int tid = threadIdx.x, bx = blockIdx.x;
  const int path = bx >> 10;
  const int mblk = bx & 1023;
  const float* X = (path == 0) ? cur : pre;
  const short* Wp = (path == 0) ? Wq : (path == 1) ? Wk : Wv;
  const float* t1 = T + path * 256;
  const float* t2 = t1 + 128;
  const int b = mblk >> 7;
  const int pl0 = (mblk & 127) * 128;

  // stage A-tile raw bf16 + row stats
  {
    const int r = tid >> 1, hf = tid & 1;
    const float* src = X + ((size_t)(mblk * 128 + r)) * 128 + hf * 64;
    float s1 = 0.f, s2 = 0.f;
#pragma unroll
    for (int g = 0; g < 8; g++) {
      const f32x4 v0 = *(const f32x4*)(src + g * 8);
      const f32x4 v1 = *(const f32x4*)(src + g * 8 + 4);
      s16x8 o;
#pragma unroll
      for (int j = 0; j < 4; j++) {
        s1 += v0[j] + v1[j]; s2 += v0[j] * v0[j] + v1[j] * v1[j];
        o[j] = f2bf(v0[j]); o[4 + j] = f2bf(v1[j]);
      }
      *(s16x8*)&At[r][hf * 64 + g * 8] = o;
    }
    s1 += __shfl_xor(s1, 1);
    s2 += __shfl_xor(s2, 1);
    if (hf == 0) {
      const float mu = s1 * (1.f / 128.f);
      const float var = s2 * (1.f / 128.f) - mu * mu;
      rowstat[r] = (f32x2){mu, rsqrtf(var + 1e-5f)};
    }
  }
  __syncthreads();

  const int wv = tid >> 6, lane = tid & 63, l16 = lane & 15, quad = lane >> 4, kof = quad * 8;
  f32x4 acc[2][8];
#pragma unroll
  for (int i = 0; i < 2; i++)
#pragma unroll
    for (int j = 0; j < 8; j++) acc[i][j] = (f32x4){0.f, 0.f, 0.f, 0.f};

  if (path < 2) {   // rows = pos (LDS A), cols = o (global W' B)
#pragma unroll
    for (int ks = 0; ks < 4; ks++) {
      const int kb = ks * 32 + kof;
      const bf16x8 a0 = *(const bf16x8*)&At[wv * 32 + l16][kb];
      const bf16x8 a1 = *(const bf16x8*)&At[wv * 32 + 16 + l16][kb];
#pragma unroll
      for (int j = 0; j < 8; j++) {
        const bf16x8 bv = *(const bf16x8*)(Wp + (j * 16 + l16) * 128 + kb);
        acc[0][j] = __builtin_amdgcn_mfma_f32_16x16x32_bf16(a0, bv, acc[0][j], 0, 0, 0);
        acc[1][j] = __builtin_amdgcn_mfma_f32_16x16x32_bf16(a1, bv, acc[1][j], 0, 0, 0);
      }
    }
    short* Yout = (path == 0) ? Yq : Yk;
    float t1v[8], t2v[8];
#pragma unroll
    for (int j = 0; j < 8; j++) { const int o = j * 16 + l16; t1v[j] = t1[o]; t2v[j] = t2[o]; }
#pragma unroll
    for (int i = 0; i < 2; i++) {
      const int pr = wv * 32 + i * 16 + quad * 4;
      f32x2 st[4];
#pragma unroll
      for (int rg = 0; rg < 4; rg++) st[rg] = rowstat[pr + rg];
#pragma unroll
      for (int j = 0; j < 8; j++) {
        const int o = j * 16 + l16;
        s16x4 pk;
#pragma unroll
        for (int rg = 0; rg < 4; rg++) {
          const float y = st[rg].y * acc[i][j][rg] - st[rg].x * st[rg].y * t1v[j] + t2v[j];
          pk[rg] = f2bf(y);
        }
        *(s16x4*)(Yout + ((size_t)(b * 128 + o)) * 16384 + pl0 + pr) = pk;
      }
    }
  } else {          // v: rows = o (global W' A), cols = pos (LDS B)
#pragma unroll
    for (int ks = 0; ks < 4; ks++) {
      const int kb = ks * 32 + kof;
      const bf16x8 w0 = *(const bf16x8*)(Wp + (wv * 32 + l16) * 128 + kb);
      const bf16x8 w1 = *(const bf16x8*)(Wp + (wv * 32 + 16 + l16) * 128 + kb);
#pragma unroll
      for (int j = 0; j < 8; j++) {
        const bf16x8 xv = *(const bf16x8*)&At[j * 16 + l16][kb];
        acc[0][j] = __builtin_amdgcn_mfma_f32_16x16x32_bf16(w0, xv, acc[0][j], 0, 0, 0);
        acc[1][j] = __builtin_amdgcn_mfma_f32_16x16x32_bf16(w1, xv, acc[1][j], 0, 0, 0);
      }
    }
#pragma unroll
    for (int i = 0; i < 2; i++) {
      const int o0 = wv * 32 + i * 16 + quad * 4;
      const f32x4 t14 = *(const f32x4*)(t1 + o0);
      const f32x4 t24 = *(const f32x4*)(t2 + o0);
#pragma unroll
      for (int j = 0; j < 8; j++) {
        const int pc = j * 16 + l16;
        const f32x2 st = rowstat[pc];
        s16x4 pk;
#pragma unroll
        for (int rg = 0; rg < 4; rg++) {
          const float y = st.y * acc[i][j][rg] - st.x * st.y * t14[rg] + t24[rg];
          pk[rg] = f2bf(y);
        }
        *(s16x4*)(Yv + ((size_t)(mblk * 128 + pc)) * 128 + o0) = pk;
      }
    }
  }
}

// ---------------------------------------------------------------------------
// K2: depthwise 3x3 on planar [c-plane][128x128] bf16, vectorized sliding
//  window along w. grid 3072 = path(3) x b(8) x c(128); block 256 =
//  (row 128) x (w-half 2). Also per-plane sum-of-squares for q,k norms.
// ---------------------------------------------------------------------------
__global__ __launch_bounds__(256, 4)
void k2_plane(const short* __restrict__ Yq, const short* __restrict__ Yk,
              const short* __restrict__ Yv,
              const float* __restrict__ qw2, const float* __restrict__ qb2,
              const float* __restrict__ kvw2, const float* __restrict__ kvb2,
              short* __restrict__ qo, short* __restrict__ ko, short* __restrict__ vo,
              float* __restrict__ nq, float* __restrict__ nk)
{
  __shared__ __attribute__((aligned(16))) short tile[130][144]; // inner at [h+1][w+8]
  __shared__ float red[256];
  const int tid = threadIdx.x, bx = blockIdx.x;
  const int path = bx >> 10, rem = bx & 1023;
  const int b = rem >> 7, c = rem & 127;
  const short* in; const float* w2p; float bsv; short* outp; float* np;
  if (path == 0)      { in = Yq; w2p = qw2 + c * 9;          bsv = qb2[c];        outp = qo; np = nq; }
  else if (path == 1) { in = Yk; w2p = kvw2 + c * 9;         bsv = kvb2[c];       outp = ko; np = nk; }
  else                { in = Yv; w2p = kvw2 + (128 + c) * 9; bsv = kvb2[128 + c]; outp = vo; np = nullptr; }

  const short* plane = in + ((size_t)(b * 128 + c)) * 16384;
#pragma unroll
  for (int g = 0; g < 8; g++) {
    const int e = (g * 256 + tid) * 8;
    *(s16x8*)&tile[(e >> 7) + 1][(e & 127) + 8] = *(const s16x8*)(plane + e);
  }
  const s16x8 z8 = (s16x8){0, 0, 0, 0, 0, 0, 0, 0};
  if (tid < 128) *(s16x8*)&tile[tid + 1][136] = z8;          // right halo
  if (tid < 36) { const int rr = (tid / 18) * 129, cc = (tid % 18) * 8; *(s16x8*)&tile[rr][cc] = z8; }
  __syncthreads();

  float wt[9];
#pragma unroll
  for (int j = 0; j < 9; j++) wt[j] = w2p[j];
  const int rr = tid >> 1, hfc = tid & 1;

  float A0[8], A1[8], A2[8];
  {
    const int ca = 8 + hfc * 64;
    const s16x8 a0 = *(const s16x8*)&tile[rr][ca];
    const s16x8 a1 = *(const s16x8*)&tile[rr + 1][ca];
    const s16x8 a2 = *(const s16x8*)&tile[rr + 2][ca];
#pragma unroll
    for (int x = 0; x < 8; x++) { A0[x] = bf2f(a0[x]); A1[x] = bf2f(a1[x]); A2[x] = bf2f(a2[x]); }
  }
  float p0, p1, p2;
  if (hfc) { p0 = bf2f(tile[rr][71]); p1 = bf2f(tile[rr + 1][71]); p2 = bf2f(tile[rr + 2][71]); }
  else { p0 = p1 = p2 = 0.f; }

  float ss = 0.f;
  short* oplane = outp + ((size_t)(b * 128 + c)) * 16384 + rr * 128 + hfc * 64;
#pragma unroll
  for (int g = 0; g < 8; g++) {
    const int cb = 16 + hfc * 64 + g * 8;
    const s16x8 b0 = *(const s16x8*)&tile[rr][cb];
    const s16x8 b1 = *(const s16x8*)&tile[rr + 1][cb];
    const s16x8 b2 = *(const s16x8*)&tile[rr + 2][cb];
    float B0[8], B1[8], B2[8];
#pragma unroll
    for (int x = 0; x < 8; x++) { B0[x] = bf2f(b0[x]); B1[x] = bf2f(b1[x]); B2[x] = bf2f(b2[x]); }
    s16x8 ov;
#pragma unroll
    for (int x = 0; x < 8; x++) {
      const float l0 = x ? A0[x - 1] : p0, l1 = x ? A1[x - 1] : p1, l2 = x ? A2[x - 1] : p2;
      const float r0 = (x < 7) ? A0[x + 1] : B0[0];
      const float r1 = (x < 7) ? A1[x + 1] : B1[0];
      const float r2 = (x < 7) ? A2[x + 1] : B2[0];
      float s = bsv;
      s += wt[0] * l0 + wt[1] * A0[x] + wt[2] * r0;
      s += wt[3] * l1 + wt[4] * A1[x] + wt[5] * r1;
      s += wt[6] * l2 + wt[7] * A2[x] + wt[8] * r2;
      ov[x] = f2bf(s); ss += s * s;
    }
    *(s16x8*)(oplane + g * 8) = ov;
    p0 = A0[7]; p1 = A1[7]; p2 = A2[7];
#pragma unroll
    for (int x = 0; x < 8; x++) { A0[x] = B0[x]; A1[x] = B1[x]; A2[x] = B2[x]; }
  }
  red[tid] = ss;
  __syncthreads();
  if (tid < 64) {
    float t = red[tid] + red[tid + 64] + red[tid + 128] + red[tid + 192];
#pragma unroll
    for (int m = 32; m >= 1; m >>= 1) t += __shfl_xor(t, m);
    if (tid == 0 && np) np[b * 128 + c] = t;
  }
}

// ---------------------------------------------------------------------------
// K3: Gram partials from planar q,k — MFMA frags DIRECT from global.
//  grid 512 = b(8) x 64 n-splits of 256; block 256 computes full 128x128.
// ---------------------------------------------------------------------------
__global__ __launch_bounds__(256, 2)
void k3_gram(const short* __restrict__ qo, const short* __restrict__ ko,
             float* __restrict__ Gp)
{
  const int tid = threadIdx.x, bx = blockIdx.x;
  const int b = bx >> 6, sp = bx & 63;
  const int wv = tid >> 6, lane = tid & 63, l16 = lane & 15, quad = lane >> 4, kof = quad * 8;
  f32x4 acc[2][8];
#pragma unroll
  for (int i = 0; i < 2; i++)
#pragma unroll
    for (int j = 0; j < 8; j++) acc[i][j] = (f32x4){0.f, 0.f, 0.f, 0.f};

  const short* qb = qo + (size_t)b * 128 * 16384 + sp * 256 + kof;
  const short* kb = ko + (size_t)b * 128 * 16384 + sp * 256 + kof;
#pragma unroll
  for (int ks = 0; ks < 8; ks++) {
    const int n0 = ks * 32;
    const bf16x8 a0 = *(const bf16x8*)(qb + (size_t)(wv * 32 + l16) * 16384 + n0);
    const bf16x8 a1 = *(const bf16x8*)(qb + (size_t)(wv * 32 + 16 + l16) * 16384 + n0);
#pragma unroll
    for (int j = 0; j < 8; j++) {
      const bf16x8 bv = *(const bf16x8*)(kb + (size_t)(j * 16 + l16) * 16384 + n0);
      acc[0][j] = __builtin_amdgcn_mfma_f32_16x16x32_bf16(a0, bv, acc[0][j], 0, 0, 0);
      acc[1][j] = __builtin_amdgcn_mfma_f32_16x16x32_bf16(a1, bv, acc[1][j], 0, 0, 0);
    }
  }
  float* gp = Gp + ((size_t)(sp * 8 + b)) * 16384;
#pragma unroll
  for (int i = 0; i < 2; i++)
#pragma unroll
    for (int j = 0; j < 8; j++)
#pragma unroll
      for (int rg = 0; rg < 4; rg++)
        gp[(wv * 32 + i * 16 + quad * 4 + rg) * 128 + j * 16 + l16] = acc[i][j][rg];
}

// ---------------------------------------------------------------------------
// K4a: reduce 64 partials, l2-norm rescale, softmax over d. grid 128.
// ---------------------------------------------------------------------------
__global__ void k4a_softmax(const float* __restrict__ Gp,
                            const float* __restrict__ nq, const float* __restrict__ nk,
                            float* __restrict__ att)
{
  const int tid = threadIdx.x;
  const int b = blockIdx.x >> 4, cb = (blockIdx.x & 15) * 8;
  const int r = tid >> 5, dsi = tid & 31;
  const int c = cb + r, d0 = dsi * 4;
  f32x4 a = (f32x4){0.f, 0.f, 0.f, 0.f};
  for (int ks = 0; ks < 64; ks++)
    a += *(const f32x4*)(Gp + ((size_t)(ks * 8 + b)) * 16384 + c * 128 + d0);
  const float qn = fmaxf(sqrtf(nq[b * 128 + c]), 1e-12f);
  f32x4 sc;
#pragma unroll
  for (int j = 0; j < 4; j++) {
    const float kn = fmaxf(sqrtf(nk[b * 128 + d0 + j]), 1e-12f);
    sc[j] = a[j] / (qn * kn);
  }
  float mx = fmaxf(fmaxf(sc[0], sc[1]), fmaxf(sc[2], sc[3]));
#pragma unroll
  for (int m = 16; m >= 1; m >>= 1) mx = fmaxf(mx, __shfl_xor(mx, m));
  f32x4 e; float sum = 0.f;
#pragma unroll
  for (int j = 0; j < 4; j++) { e[j] = __expf(sc[j] - mx); sum += e[j]; }
#pragma unroll
  for (int m = 16; m >= 1; m >>= 1) sum += __shfl_xor(sum, m);
  const float inv = 1.f / sum;
  f32x4 o;
#pragma unroll
  for (int j = 0; j < 4; j++) o[j] = e[j] * inv;
  *(f32x4*)(att + (size_t)b * 16384 + c * 128 + d0) = o;
}

// ---------------------------------------------------------------------------
// K4b: M[b][o][d] = sum_c out_w[o][c]*att[b][c][d], bf16.
//  grid 128 = b(8) x 16 d-groups of 8; att tile staged in LDS.
// ---------------------------------------------------------------------------
__global__ void k4b_mw(const float* __restrict__ att, const float* __restrict__ outw,
                       short* __restrict__ Mb)
{
  __shared__ float at[128][8];
  const int tid = threadIdx.x, bx = blockIdx.x;
  const int b = bx >> 4, d0 = (bx & 15) * 8;
  {
    const int cc = tid >> 1, q = tid & 1;
    *(f32x4*)&at[cc][q * 4] = *(const f32x4*)(att + (size_t)b * 16384 + cc * 128 + d0 + q * 4);
  }
  __syncthreads();
  const int o = tid & 127, dq = (tid >> 7) * 4;
  f32x4 acc = (f32x4){0.f, 0.f, 0.f, 0.f};
  const float* wr = outw + o * 128;
  for (int cc = 0; cc < 128; cc++) {
    const float w = wr[cc];
    const f32x4 a = *(const f32x4*)&at[cc][dq];
    acc += w * a;
  }
  s16x4 pk;
#pragma unroll
  for (int rg = 0; rg < 4; rg++) pk[rg] = f2bf(acc[rg]);
  *(s16x4*)(Mb + ((size_t)(b * 128 + o)) * 128 + d0 + dq) = pk;
}

// ---------------------------------------------------------------------------
// K5: out[b][n][o] = sum_d M[o][d]*v[d][n] + out_b[o] + cur[b][n][o].
//  v planar -> LDS transpose staging; D rows=o cols=pos; f32x4 stores.
//  grid 1024 = b(8) x 128 pos-chunks.
// ---------------------------------------------------------------------------
__global__ __launch_bounds__(256, 3)
void k5_out(const short* __restrict__ Mb, const short* __restrict__ vp,
            const float* __restrict__ outb, const float* __restrict__ cur,
            float* __restrict__ out)
{
  __shared__ __attribute__((aligned(16))) short Vt[128][136];
  const int tid = threadIdx.x;
  const int b = blockIdx.x >> 7, nb = (blockIdx.x & 127) * 128;
  {
    const int d = tid >> 1, hf = tid & 1;
    const short* src = vp + ((size_t)(b * 128 + d)) * 16384 + nb + hf * 64;
#pragma unroll
    for (int g = 0; g < 8; g++) {
      const s16x8 v = *(const s16x8*)(src + g * 8);
#pragma unroll
      for (int x = 0; x < 8; x++) Vt[hf * 64 + g * 8 + x][d] = v[x];
    }
  }
  __syncthreads();
  const int wv = tid >> 6, lane = tid & 63, l16 = lane & 15, quad = lane >> 4, kof = quad * 8;
  f32x4 acc[2][8];
#pragma unroll
  for (int i = 0; i < 2; i++)
#pragma unroll
    for (int j = 0; j < 8; j++) acc[i][j] = (f32x4){0.f, 0.f, 0.f, 0.f};

  const short* m0 = Mb + ((size_t)(b * 128 + wv * 32 + l16)) * 128;
  const short* m1 = m0 + 16 * 128;
#pragma unroll
  for (int ks = 0; ks < 4; ks++) {
    const int kb = ks * 32 + kof;
    const bf16x8 a0 = *(const bf16x8*)(m0 + kb);
    const bf16x8 a1 = *(const bf16x8*)(m1 + kb);
#pragma unroll
    for (int j = 0; j < 8; j++) {
      const bf16x8 bv = *(const bf16x8*)&Vt[j * 16 + l16][kb];
      acc[0][j] = __builtin_amdgcn_mfma_f32_16x16x32_bf16(a0, bv, acc[0][j], 0, 0, 0);
      acc[1][j] = __builtin_amdgcn_mfma_f32_16x16x32_bf16(a1, bv, acc[1][j], 0, 0, 0);
    }
  }
#pragma unroll
  for (int i = 0; i < 2; i++) {
    const int o0 = wv * 32 + i * 16 + quad * 4;
    const f32x4 bias = *(const f32x4*)(outb + o0);
#pragma unroll
    for (int j = 0; j < 8; j++) {
      const int pos = nb + j * 16 + l16;
      const size_t idx = ((size_t)(b * 16384 + pos)) * 128 + o0;
      const f32x4 cv = *(const f32x4*)(cur + idx);
      f32x4 rr;
#pragma unroll
      for (int rg = 0; rg < 4; rg++) rr[rg] = acc[i][j][rg] + bias[rg] + cv[rg];
      *(f32x4*)(out + idx) = rr;
    }
  }
}

// ---------------------------------------------------------------------------
extern "C" void kernel_launch(void* const* d_in, const int* in_sizes, int n_in,
                              void* d_out, int out_size, void* d_ws, size_t ws_size,
                              hipStream_t stream) {
  const float* pre  = (const float*)d_in[0];
  const float* cur  = (const float*)d_in[1];
  const float* ln1w = (const float*)d_in[2];
  const float* ln1b = (const float*)d_in[3];
  const float* ln2w = (const float*)d_in[4];
  const float* ln2b = (const float*)d_in[5];
  const float* qw1  = (const float*)d_in[6];
  const float* qb1  = (const float*)d_in[7];
  const float* qw2  = (const float*)d_in[8];
  const float* qb2  = (const float*)d_in[9];
  const float* kvw1 = (const float*)d_in[10];
  const float* kvb1 = (const float*)d_in[11];
  const float* kvw2 = (const float*)d_in[12];
  const float* kvb2 = (const float*)d_in[13];
  const float* outw = (const float*)d_in[14];
  const float* outb = (const float*)d_in[15];

  char* ws = (char*)d_ws;
  short* Yq  = (short*)(ws);                 // 32M planar [b*c][n]
  short* Yk  = (short*)(ws + 33554432);      // 32M planar
  short* Yv  = (short*)(ws + 67108864);      // 32M planar
  short* qo  = (short*)(ws + 100663296);     // 32M planar
  short* ko  = (short*)(ws + 134217728);     // 32M planar
  short* vo  = (short*)(ws + 167772160);     // 32M planar
  float* Gp  = (float*)(ws);                 // 32M, aliases Yq (dead after k2)
  float* att = (float*)(ws + 33554432);      // 512K, aliases Yk
  short* Mb  = (short*)(ws + 34078720);      // 256K, aliases Yk
  char*  sm  = ws + 201326592;
  short* Wq  = (short*)(sm);                 // 32K
  short* Wk  = (short*)(sm + 32768);
  short* Wv  = (short*)(sm + 65536);
  float* T   = (float*)(sm + 98304);         // 3K
  float* nq  = (float*)(sm + 102400);        // 4K
  float* nk  = (float*)(sm + 106496);        // 4K

  hipLaunchKernelGGL(k0_prep, dim3(3), dim3(256), 0, stream,
                     qw1, qb1, kvw1, kvb1, ln1w, ln1b, ln2w, ln2b, Wq, Wk, Wv, T);
  hipLaunchKernelGGL(k1_ln_gemm, dim3(3072), dim3(256), 0, stream,
                     cur, pre, Wq, Wk, Wv, T, Yq, Yk, Yv);
  hipLaunchKernelGGL(k2_plane, dim3(3072), dim3(256), 0, stream,
                     Yq, Yk, Yv, qw2, qb2, kvw2, kvb2, qo, ko, vo, nq, nk);
  hipLaunchKernelGGL(k3_gram, dim3(512), dim3(256), 0, stream, qo, ko, Gp);
  hipLaunchKernelGGL(k4a_softmax, dim3(128), dim3(256), 0, stream, Gp, nq, nk, att);
  hipLaunchKernelGGL(k4b_mw, dim3(128), dim3(256), 0, stream, att, outw, Mb);
  hipLaunchKernelGGL(k5_out, dim3(1024), dim3(256), 0, stream, Mb, vo, outb, cur, (float*)d_out);
}